// Round 3
// baseline (1547.033 us; speedup 1.0000x reference)
//
#include <hip/hip_runtime.h>

#define NT 64
#define DIMC 256
#define NHEADS 8
#define NWIN 2048
#define TOPK_ 51
#define SCALE_ 0.17677669529663687f

// Split-bf16 GEMM scheme: fp32 value v -> hi=bf16(v), lo=bf16(v-hi).
// v*w ~= hi_v*hi_w + hi_v*lo_w + lo_v*hi_w  (3 MFMAs, fp32 accum, rel err ~1e-5).
//
// MFMA v_mfma_f32_16x16x32_bf16 lane mappings used (m89/m91-verified C/D; A/B the
// AMD-doc convention, cross-consistent with the guide's swapped-QK^T derivation):
//   A frag (8 bf16): A[l%16][8*(l/16)+j]
//   B frag (8 bf16): B[8*(l/16)+j][l%16]
//   D (4 f32):       D[4*(l/16)+r][l%16]
//
// ws layout (bytes):
//   [0, 393216)        wqhi: qkv weights hi, fragment-packed [ct=48][ks=8][lane=64][8]
//   [393216, 786432)   wqlo: qkv weights lo
//   [786432, 917504)   wphi: proj weights hi, [ct=16][ks=8][lane=64][8]
//   [917504, 1048576)  wplo: proj weights lo
//   [1048576, 2097152) masks: 2048 x 64 u64

typedef short bf16x8 __attribute__((ext_vector_type(8)));
typedef float f32x4 __attribute__((ext_vector_type(4)));

__device__ __forceinline__ unsigned short f2bf(float f) {
    unsigned u = __float_as_uint(f);
    u += 0x7fffu + ((u >> 16) & 1u);           // round-to-nearest-even
    return (unsigned short)(u >> 16);
}
__device__ __forceinline__ float bf2f(unsigned short h) {
    return __uint_as_float(((unsigned)h) << 16);
}
__device__ __forceinline__ void cvt4(const float4& v, ushort4& h, ushort4& lo) {
    h.x = f2bf(v.x); h.y = f2bf(v.y); h.z = f2bf(v.z); h.w = f2bf(v.w);
    lo.x = f2bf(v.x - bf2f(h.x)); lo.y = f2bf(v.y - bf2f(h.y));
    lo.z = f2bf(v.z - bf2f(h.z)); lo.w = f2bf(v.w - bf2f(h.w));
}

// ---------------- kernel 0: weight split + fragment pack ----------------
__global__ __launch_bounds__(256) void k_prep(
    const float* __restrict__ qkv_w, const float* __restrict__ proj_w,
    unsigned short* __restrict__ wqhi, unsigned short* __restrict__ wqlo,
    unsigned short* __restrict__ wphi, unsigned short* __restrict__ wplo)
{
    int e = blockIdx.x * 256 + threadIdx.x;      // [0, 262144)
    float v; unsigned short* hi; unsigned short* lo; int di;
    if (e < 196608) {
        int j = e & 7, l = (e >> 3) & 63, ks = (e >> 9) & 7, ct = e >> 12;  // ct 0..47
        int o = ct * 16 + (l & 15);
        int k = ks * 32 + 8 * (l >> 4) + j;
        v = qkv_w[o * 256 + k]; hi = wqhi; lo = wqlo; di = e;
    } else {
        int e2 = e - 196608;
        int j = e2 & 7, l = (e2 >> 3) & 63, ks = (e2 >> 9) & 7, ct = e2 >> 12; // ct 0..15
        int o = ct * 16 + (l & 15);
        int k = ks * 32 + 8 * (l >> 4) + j;
        v = proj_w[o * 256 + k]; hi = wphi; lo = wplo; di = e2;
    }
    unsigned short h = f2bf(v);
    hi[di] = h;
    lo[di] = f2bf(v - bf2f(h));
}

// ---------------- kernel 1: var self-similarity + top-51 mask (unchanged) ----------------
__global__ __launch_bounds__(256) void k_modulation(
    const float* __restrict__ var, unsigned long long* __restrict__ masks)
{
    __shared__ float vs[64][257];
    __shared__ float ss[64][65];
    __shared__ unsigned short bits[64][4];
    const int b = blockIdx.x, t = threadIdx.x;

    const float* vp = var + (size_t)b * (NT * DIMC);
    #pragma unroll
    for (int i = 0; i < 16; ++i) {
        int idx = t + i * 256;
        float4 v = reinterpret_cast<const float4*>(vp)[idx];
        int n = idx >> 6, k = (idx & 63) << 2;
        vs[n][k + 0] = v.x; vs[n][k + 1] = v.y; vs[n][k + 2] = v.z; vs[n][k + 3] = v.w;
    }
    __syncthreads();

    {
        const int n0 = (t >> 4) << 2, m0 = (t & 15) << 2;
        float acc[4][4];
        #pragma unroll
        for (int i = 0; i < 4; ++i)
            #pragma unroll
            for (int j = 0; j < 4; ++j) acc[i][j] = 0.f;
        #pragma unroll 4
        for (int k = 0; k < 256; ++k) {
            float av[4], bv[4];
            #pragma unroll
            for (int i = 0; i < 4; ++i) av[i] = vs[n0 + i][k];
            #pragma unroll
            for (int j = 0; j < 4; ++j) bv[j] = vs[m0 + j][k];
            #pragma unroll
            for (int i = 0; i < 4; ++i)
                #pragma unroll
                for (int j = 0; j < 4; ++j) acc[i][j] += av[i] * bv[j];
        }
        #pragma unroll
        for (int i = 0; i < 4; ++i)
            #pragma unroll
            for (int j = 0; j < 4; ++j) ss[n0 + i][m0 + j] = acc[i][j];
    }
    __syncthreads();

    // top-51 with jax.lax.top_k tie semantics (stable: lower index wins)
    {
        const int n = t >> 2, q = t & 3, mb = q * 16;
        float sv[16];
        int cnt[16];
        #pragma unroll
        for (int j = 0; j < 16; ++j) { sv[j] = ss[n][mb + j]; cnt[j] = 0; }
        for (int p = 0; p < 64; ++p) {
            float vv = ss[n][p];
            #pragma unroll
            for (int j = 0; j < 16; ++j)
                cnt[j] += (vv > sv[j] || (vv == sv[j] && p < mb + j)) ? 1 : 0;
        }
        unsigned int w = 0;
        #pragma unroll
        for (int j = 0; j < 16; ++j) if (cnt[j] < TOPK_) w |= (1u << j);
        bits[n][q] = (unsigned short)w;
    }
    __syncthreads();
    if (t < 64) {
        unsigned long long w =
            (unsigned long long)bits[t][0]
          | ((unsigned long long)bits[t][1] << 16)
          | ((unsigned long long)bits[t][2] << 32)
          | ((unsigned long long)bits[t][3] << 48);
        masks[(size_t)b * 64 + t] = w;
    }
}

// ---------------- kernel 2: MFMA qkv -> fp32 attention (2 heads/pass x 4) ----------------
__global__ __launch_bounds__(512) void k_attn(
    const float* __restrict__ x,
    const float* __restrict__ qkv_b,
    const float* __restrict__ rpb_table,
    const unsigned short* __restrict__ wqhi,
    const unsigned short* __restrict__ wqlo,
    const unsigned long long* __restrict__ masks,
    float* __restrict__ aout)
{
    __shared__ alignas(16) unsigned short xhi[64][264];  // +8 pad: rows 528B, 16B-aligned
    __shared__ alignas(16) unsigned short xlo[64][264];
    __shared__ float q2[64][67];                         // heads (2p, 2p+1) side by side
    __shared__ float k2[64][67];
    __shared__ float v2[64][67];

    const int b = blockIdx.x, t = threadIdx.x;
    const int l = t & 63;
    const int wave = __builtin_amdgcn_readfirstlane(t >> 6);
    const int hg   = wave >> 2;            // attention head-group
    const int tl   = t & 255;
    const int arow = tl >> 2, aq = tl & 3;
    const int rt   = wave >> 1;            // MFMA row-tile (each rt covered by 2 waves)
    const int ctl0 = 6 * (wave & 1);       // first of this wave's 6 col-tiles (of 12)

    // stage x -> bf16 hi/lo
    const float* xp = x + (size_t)b * (NT * DIMC);
    #pragma unroll
    for (int i = 0; i < 8; ++i) {
        int idx = t + i * 512;             // float4 index in [0,4096)
        float4 v = reinterpret_cast<const float4*>(xp)[idx];
        int n = idx >> 6, kq = (idx & 63) << 2;
        ushort4 h, lo;
        cvt4(v, h, lo);
        *reinterpret_cast<ushort4*>(&xhi[n][kq]) = h;
        *reinterpret_cast<ushort4*>(&xlo[n][kq]) = lo;
    }
    const unsigned long long mword = masks[(size_t)b * 64 + arow];
    __syncthreads();

    const int arow16 = rt * 16 + (l & 15); // A-frag row
    const int kgrp   = 8 * (l >> 4);       // A/B-frag k-subgroup

    for (int p = 0; p < 4; ++p) {
        // ---- qkv for heads (2p, 2p+1) via split-bf16 MFMA ----
        f32x4 acc[6];
        #pragma unroll
        for (int c = 0; c < 6; ++c) {
            const int ctl = ctl0 + c;
            const int mat = ctl >> 2, within = ctl & 3;
            const int o = mat * 256 + p * 64 + within * 16 + (l & 15);
            const float bv = qkv_b[o];
            acc[c] = (f32x4){bv, bv, bv, bv};
        }
        for (int ks = 0; ks < 8; ++ks) {
            const bf16x8 ah = *reinterpret_cast<const bf16x8*>(&xhi[arow16][ks * 32 + kgrp]);
            const bf16x8 al = *reinterpret_cast<const bf16x8*>(&xlo[arow16][ks * 32 + kgrp]);
            #pragma unroll
            for (int c = 0; c < 6; ++c) {
                const int ctl = ctl0 + c;
                const int ct = (ctl >> 2) * 16 + 4 * p + (ctl & 3);
                const int off = ct * 4096 + ks * 512 + l * 8;
                const bf16x8 bh = *reinterpret_cast<const bf16x8*>(wqhi + off);
                const bf16x8 bl = *reinterpret_cast<const bf16x8*>(wqlo + off);
                acc[c] = __builtin_amdgcn_mfma_f32_16x16x32_bf16(ah, bh, acc[c], 0, 0, 0);
                acc[c] = __builtin_amdgcn_mfma_f32_16x16x32_bf16(ah, bl, acc[c], 0, 0, 0);
                acc[c] = __builtin_amdgcn_mfma_f32_16x16x32_bf16(al, bh, acc[c], 0, 0, 0);
            }
        }
        // D -> LDS q2/k2/v2 (col = hh*32 + d; q folded with SCALE)
        {
            const int rowb = rt * 16 + 4 * (l >> 4);
            #pragma unroll
            for (int c = 0; c < 6; ++c) {
                const int ctl = ctl0 + c;
                const int mat = ctl >> 2, within = ctl & 3;
                const int col = (within >> 1) * 32 + (within & 1) * 16 + (l & 15);
                float* dst = mat == 0 ? &q2[0][0] : (mat == 1 ? &k2[0][0] : &v2[0][0]);
                const float sc = mat == 0 ? SCALE_ : 1.0f;
                #pragma unroll
                for (int r = 0; r < 4; ++r)
                    dst[(rowb + r) * 67 + col] = acc[c][r] * sc;
            }
        }
        __syncthreads();

        // ---- fp32 attention for head h = 2p + hg (4 lanes/row, 16 key-cols each) ----
        {
            const int h = 2 * p + hg;
            float qreg[32];
            const float* qrow = &q2[arow][hg * 32];
            #pragma unroll
            for (int d = 0; d < 32; ++d) qreg[d] = qrow[d];
            float pbuf[16];
            float mx = -1e30f;
            #pragma unroll
            for (int j = 0; j < 16; ++j) {
                const int m = aq * 16 + j;
                float s = 0.f;
                const float* krow = &k2[m][hg * 32];
                #pragma unroll
                for (int d = 0; d < 32; ++d) s += qreg[d] * krow[d];
                const float mod = ((mword >> m) & 1ull) ? 1.0f : 1.2f;
                const int ridx = ((arow >> 3) - (m >> 3) + 7) * 15 + ((arow & 7) - (m & 7) + 7);
                s = s * mod + rpb_table[ridx * NHEADS + h];
                pbuf[j] = s;
                mx = fmaxf(mx, s);
            }
            mx = fmaxf(mx, __shfl_xor(mx, 1));
            mx = fmaxf(mx, __shfl_xor(mx, 2));
            float sum = 0.f;
            #pragma unroll
            for (int j = 0; j < 16; ++j) { pbuf[j] = __expf(pbuf[j] - mx); sum += pbuf[j]; }
            sum += __shfl_xor(sum, 1);
            sum += __shfl_xor(sum, 2);
            const float inv = 1.f / sum;

            float part[32];
            #pragma unroll
            for (int d = 0; d < 32; ++d) part[d] = 0.f;
            #pragma unroll
            for (int j = 0; j < 16; ++j) {
                const int m = aq * 16 + j;
                const float pv = pbuf[j] * inv;
                const float* vrow = &v2[m][hg * 32];
                #pragma unroll
                for (int d = 0; d < 32; ++d) part[d] += pv * vrow[d];
            }
            #pragma unroll
            for (int d = 0; d < 32; ++d) {
                part[d] += __shfl_xor(part[d], 1);
                part[d] += __shfl_xor(part[d], 2);
            }
            float* op = aout + (size_t)b * (NT * DIMC) + arow * 256 + h * 32 + aq * 8;
            float4 v0, v1;
            if (aq == 0) {
                v0 = make_float4(part[0], part[1], part[2], part[3]);
                v1 = make_float4(part[4], part[5], part[6], part[7]);
            } else if (aq == 1) {
                v0 = make_float4(part[8], part[9], part[10], part[11]);
                v1 = make_float4(part[12], part[13], part[14], part[15]);
            } else if (aq == 2) {
                v0 = make_float4(part[16], part[17], part[18], part[19]);
                v1 = make_float4(part[20], part[21], part[22], part[23]);
            } else {
                v0 = make_float4(part[24], part[25], part[26], part[27]);
                v1 = make_float4(part[28], part[29], part[30], part[31]);
            }
            reinterpret_cast<float4*>(op)[0] = v0;
            reinterpret_cast<float4*>(op)[1] = v1;
        }
        __syncthreads();   // protect q2/k2/v2 before next pass overwrites
    }
}

// ---------------- kernel 3: out projection via split-bf16 MFMA, in-place on d_out ----------------
__global__ __launch_bounds__(512) void k_proj(
    const float* __restrict__ proj_b,
    const unsigned short* __restrict__ wphi,
    const unsigned short* __restrict__ wplo,
    float* __restrict__ inout)
{
    __shared__ alignas(16) unsigned short ahi[64][264];
    __shared__ alignas(16) unsigned short alo[64][264];
    const int b = blockIdx.x, t = threadIdx.x;
    const int l = t & 63;
    const int wave = __builtin_amdgcn_readfirstlane(t >> 6);

    float* base = inout + (size_t)b * (NT * DIMC);
    #pragma unroll
    for (int i = 0; i < 8; ++i) {
        int idx = t + i * 512;
        float4 v = reinterpret_cast<const float4*>(base)[idx];
        int n = idx >> 6, kq = (idx & 63) << 2;
        ushort4 h, lo;
        cvt4(v, h, lo);
        *reinterpret_cast<ushort4*>(&ahi[n][kq]) = h;
        *reinterpret_cast<ushort4*>(&alo[n][kq]) = lo;
    }
    __syncthreads();

    const int kgrp = 8 * (l >> 4);
    f32x4 acc[2][4];                      // [ct-local][rt]
    #pragma unroll
    for (int c = 0; c < 2; ++c) {
        const int col = (2 * wave + c) * 16 + (l & 15);
        const float bv = proj_b[col];
        #pragma unroll
        for (int r = 0; r < 4; ++r) acc[c][r] = (f32x4){bv, bv, bv, bv};
    }
    for (int ks = 0; ks < 8; ++ks) {
        bf16x8 ah0 = *reinterpret_cast<const bf16x8*>(&ahi[ 0 + (l & 15)][ks * 32 + kgrp]);
        bf16x8 al0 = *reinterpret_cast<const bf16x8*>(&alo[ 0 + (l & 15)][ks * 32 + kgrp]);
        bf16x8 ah1 = *reinterpret_cast<const bf16x8*>(&ahi[16 + (l & 15)][ks * 32 + kgrp]);
        bf16x8 al1 = *reinterpret_cast<const bf16x8*>(&alo[16 + (l & 15)][ks * 32 + kgrp]);
        bf16x8 ah2 = *reinterpret_cast<const bf16x8*>(&ahi[32 + (l & 15)][ks * 32 + kgrp]);
        bf16x8 al2 = *reinterpret_cast<const bf16x8*>(&alo[32 + (l & 15)][ks * 32 + kgrp]);
        bf16x8 ah3 = *reinterpret_cast<const bf16x8*>(&ahi[48 + (l & 15)][ks * 32 + kgrp]);
        bf16x8 al3 = *reinterpret_cast<const bf16x8*>(&alo[48 + (l & 15)][ks * 32 + kgrp]);
        #pragma unroll
        for (int c = 0; c < 2; ++c) {
            const int ct = 2 * wave + c;
            const int off = ct * 4096 + ks * 512 + l * 8;
            const bf16x8 bh = *reinterpret_cast<const bf16x8*>(wphi + off);
            const bf16x8 bl = *reinterpret_cast<const bf16x8*>(wplo + off);
            acc[c][0] = __builtin_amdgcn_mfma_f32_16x16x32_bf16(ah0, bh, acc[c][0], 0, 0, 0);
            acc[c][0] = __builtin_amdgcn_mfma_f32_16x16x32_bf16(ah0, bl, acc[c][0], 0, 0, 0);
            acc[c][0] = __builtin_amdgcn_mfma_f32_16x16x32_bf16(al0, bh, acc[c][0], 0, 0, 0);
            acc[c][1] = __builtin_amdgcn_mfma_f32_16x16x32_bf16(ah1, bh, acc[c][1], 0, 0, 0);
            acc[c][1] = __builtin_amdgcn_mfma_f32_16x16x32_bf16(ah1, bl, acc[c][1], 0, 0, 0);
            acc[c][1] = __builtin_amdgcn_mfma_f32_16x16x32_bf16(al1, bh, acc[c][1], 0, 0, 0);
            acc[c][2] = __builtin_amdgcn_mfma_f32_16x16x32_bf16(ah2, bh, acc[c][2], 0, 0, 0);
            acc[c][2] = __builtin_amdgcn_mfma_f32_16x16x32_bf16(ah2, bl, acc[c][2], 0, 0, 0);
            acc[c][2] = __builtin_amdgcn_mfma_f32_16x16x32_bf16(al2, bh, acc[c][2], 0, 0, 0);
            acc[c][3] = __builtin_amdgcn_mfma_f32_16x16x32_bf16(ah3, bh, acc[c][3], 0, 0, 0);
            acc[c][3] = __builtin_amdgcn_mfma_f32_16x16x32_bf16(ah3, bl, acc[c][3], 0, 0, 0);
            acc[c][3] = __builtin_amdgcn_mfma_f32_16x16x32_bf16(al3, bh, acc[c][3], 0, 0, 0);
        }
    }
    {
        const int rowo = 4 * (l >> 4);
        #pragma unroll
        for (int c = 0; c < 2; ++c) {
            const int col = (2 * wave + c) * 16 + (l & 15);
            #pragma unroll
            for (int rt = 0; rt < 4; ++rt) {
                #pragma unroll
                for (int r = 0; r < 4; ++r)
                    base[(rt * 16 + rowo + r) * 256 + col] = acc[c][rt][r];
            }
        }
    }
}

extern "C" void kernel_launch(void* const* d_in, const int* in_sizes, int n_in,
                              void* d_out, int out_size, void* d_ws, size_t ws_size,
                              hipStream_t stream)
{
    const float* x      = (const float*)d_in[0];
    const float* var    = (const float*)d_in[1];
    const float* qkv_w  = (const float*)d_in[2];
    const float* qkv_b  = (const float*)d_in[3];
    const float* proj_w = (const float*)d_in[4];
    const float* proj_b = (const float*)d_in[5];
    const float* rpb    = (const float*)d_in[6];
    float* out = (float*)d_out;

    unsigned short* wqhi = (unsigned short*)d_ws;          // 196608
    unsigned short* wqlo = wqhi + 196608;                  // 196608
    unsigned short* wphi = wqlo + 196608;                  // 65536
    unsigned short* wplo = wphi + 65536;                   // 65536
    unsigned long long* masks = (unsigned long long*)((char*)d_ws + 1048576);

    k_prep      <<<1024, 256, 0, stream>>>(qkv_w, proj_w, wqhi, wqlo, wphi, wplo);
    k_modulation<<<NWIN, 256, 0, stream>>>(var, masks);
    k_attn      <<<NWIN, 512, 0, stream>>>(x, qkv_b, rpb, wqhi, wqlo, masks, out);
    k_proj      <<<NWIN, 512, 0, stream>>>(proj_b, wphi, wplo, out);
}

// Round 4
// 1227.660 us; speedup vs baseline: 1.2601x; 1.2601x over previous
//
#include <hip/hip_runtime.h>

#define NT 64
#define DIMC 256
#define NHEADS 8
#define NWIN 2048
#define TOPK_ 51
#define SCALE_ 0.17677669529663687f

// Split-bf16 GEMM scheme: fp32 value v -> hi=bf16(v), lo=bf16(v-hi).
// v*w ~= hi_v*hi_w + hi_v*lo_w + lo_v*hi_w  (3 MFMAs, fp32 accum, rel err ~1e-5).
//
// v_mfma_f32_16x16x32_bf16 lane mappings (conventions verified by the round-3 PASS):
//   A frag (8 bf16): A[l%16][8*(l/16)+j]
//   B frag (8 bf16): B[8*(l/16)+j][l%16]
//   D (4 f32):       D[4*(l/16)+r][l%16]
//
// ws layout (bytes): unchanged from r3
//   [0, 393216)        wqhi  [393216, 786432) wqlo   (qkv weights, frag-packed [ct=48][ks=8][lane=64][8])
//   [786432, 917504)   wphi  [917504, 1048576) wplo  (proj weights, [ct=16][ks=8][lane=64][8])
//   [1048576, 2097152) masks: 2048 x 64 u64

typedef short bf16x8 __attribute__((ext_vector_type(8)));
typedef float f32x4 __attribute__((ext_vector_type(4)));

#define MFMA16 __builtin_amdgcn_mfma_f32_16x16x32_bf16

__device__ __forceinline__ unsigned short f2bf(float f) {
    unsigned u = __float_as_uint(f);
    u += 0x7fffu + ((u >> 16) & 1u);           // RNE
    return (unsigned short)(u >> 16);
}
__device__ __forceinline__ float bf2f(unsigned short h) {
    return __uint_as_float(((unsigned)h) << 16);
}
__device__ __forceinline__ void cvt8(const float* v, bf16x8& h, bf16x8& lo) {
#pragma unroll
    for (int j = 0; j < 8; ++j) {
        unsigned short hh = f2bf(v[j]);
        h[j] = (short)hh;
        lo[j] = (short)f2bf(v[j] - bf2f(hh));
    }
}

// ---------------- kernel 0: weight split + fragment pack (unchanged, passed) ----------------
__global__ __launch_bounds__(256) void k_prep(
    const float* __restrict__ qkv_w, const float* __restrict__ proj_w,
    unsigned short* __restrict__ wqhi, unsigned short* __restrict__ wqlo,
    unsigned short* __restrict__ wphi, unsigned short* __restrict__ wplo)
{
    int e = blockIdx.x * 256 + threadIdx.x;      // [0, 262144)
    float v; unsigned short* hi; unsigned short* lo; int di;
    if (e < 196608) {
        int j = e & 7, l = (e >> 3) & 63, ks = (e >> 9) & 7, ct = e >> 12;  // ct 0..47
        int o = ct * 16 + (l & 15);
        int k = ks * 32 + 8 * (l >> 4) + j;
        v = qkv_w[o * 256 + k]; hi = wqhi; lo = wqlo; di = e;
    } else {
        int e2 = e - 196608;
        int j = e2 & 7, l = (e2 >> 3) & 63, ks = (e2 >> 9) & 7, ct = e2 >> 12; // ct 0..15
        int o = ct * 16 + (l & 15);
        int k = ks * 32 + 8 * (l >> 4) + j;
        v = proj_w[o * 256 + k]; hi = wphi; lo = wplo; di = e2;
    }
    unsigned short h = f2bf(v);
    hi[di] = h;
    lo[di] = f2bf(v - bf2f(h));
}

// ---------------- kernel 1: var self-similarity + top-51 mask (unchanged, passed) ----------------
__global__ __launch_bounds__(256) void k_modulation(
    const float* __restrict__ var, unsigned long long* __restrict__ masks)
{
    __shared__ float vs[64][257];
    __shared__ float ss[64][65];
    __shared__ unsigned short bits[64][4];
    const int b = blockIdx.x, t = threadIdx.x;

    const float* vp = var + (size_t)b * (NT * DIMC);
    #pragma unroll
    for (int i = 0; i < 16; ++i) {
        int idx = t + i * 256;
        float4 v = reinterpret_cast<const float4*>(vp)[idx];
        int n = idx >> 6, k = (idx & 63) << 2;
        vs[n][k + 0] = v.x; vs[n][k + 1] = v.y; vs[n][k + 2] = v.z; vs[n][k + 3] = v.w;
    }
    __syncthreads();

    {
        const int n0 = (t >> 4) << 2, m0 = (t & 15) << 2;
        float acc[4][4];
        #pragma unroll
        for (int i = 0; i < 4; ++i)
            #pragma unroll
            for (int j = 0; j < 4; ++j) acc[i][j] = 0.f;
        #pragma unroll 4
        for (int k = 0; k < 256; ++k) {
            float av[4], bv[4];
            #pragma unroll
            for (int i = 0; i < 4; ++i) av[i] = vs[n0 + i][k];
            #pragma unroll
            for (int j = 0; j < 4; ++j) bv[j] = vs[m0 + j][k];
            #pragma unroll
            for (int i = 0; i < 4; ++i)
                #pragma unroll
                for (int j = 0; j < 4; ++j) acc[i][j] += av[i] * bv[j];
        }
        #pragma unroll
        for (int i = 0; i < 4; ++i)
            #pragma unroll
            for (int j = 0; j < 4; ++j) ss[n0 + i][m0 + j] = acc[i][j];
    }
    __syncthreads();

    // top-51 with jax.lax.top_k tie semantics (stable: lower index wins)
    {
        const int n = t >> 2, q = t & 3, mb = q * 16;
        float sv[16];
        int cnt[16];
        #pragma unroll
        for (int j = 0; j < 16; ++j) { sv[j] = ss[n][mb + j]; cnt[j] = 0; }
        for (int p = 0; p < 64; ++p) {
            float vv = ss[n][p];
            #pragma unroll
            for (int j = 0; j < 16; ++j)
                cnt[j] += (vv > sv[j] || (vv == sv[j] && p < mb + j)) ? 1 : 0;
        }
        unsigned int w = 0;
        #pragma unroll
        for (int j = 0; j < 16; ++j) if (cnt[j] < TOPK_) w |= (1u << j);
        bits[n][q] = (unsigned short)w;
    }
    __syncthreads();
    if (t < 64) {
        unsigned long long w =
            (unsigned long long)bits[t][0]
          | ((unsigned long long)bits[t][1] << 16)
          | ((unsigned long long)bits[t][2] << 32)
          | ((unsigned long long)bits[t][3] << 48);
        masks[(size_t)b * 64 + t] = w;
    }
}

// ---------------- kernel 2: MFMA qkv -> MFMA attention (2 heads/pass x 4 passes) ----------------
// LDS 61.5 KB -> 2 blocks/CU. P buffer aliases q/k buffers (dead after QK^T).
__global__ __launch_bounds__(512) void k_attn(
    const float* __restrict__ x,
    const float* __restrict__ qkv_b,
    const float* __restrict__ rpb_table,
    const unsigned short* __restrict__ wqhi,
    const unsigned short* __restrict__ wqlo,
    const unsigned long long* __restrict__ masks,
    float* __restrict__ aout)
{
    // smem map (bytes):
    //   [0,9216)      qhi [64][72]     \ aliased after QK^T by
    //   [9216,18432)  qlo [64][72]      > phi [2][64][72] (0..18432)
    //   [18432,27648) khi [64][72]      > plo [2][64][72] (18432..36864)
    //   [27648,36864) klo [64][72]     /
    //   [36864,46080) vThi [2][32][72]
    //   [46080,55296) vTlo [2][32][72]
    //   [55296,62496) rpb_l [1800] f32
    //   [62496,63008) mask_l [64] u64
    __shared__ alignas(16) char smem[63008];
    unsigned short* qhi  = (unsigned short*)(smem);
    unsigned short* qlo  = (unsigned short*)(smem + 9216);
    unsigned short* khi  = (unsigned short*)(smem + 18432);
    unsigned short* klo  = (unsigned short*)(smem + 27648);
    unsigned short* phi  = (unsigned short*)(smem);          // [2][64][72]
    unsigned short* plo  = (unsigned short*)(smem + 18432);  // [2][64][72]
    unsigned short* vThi = (unsigned short*)(smem + 36864);  // [2][32][72]
    unsigned short* vTlo = (unsigned short*)(smem + 46080);
    float* rpb_l = (float*)(smem + 55296);
    unsigned long long* mask_l = (unsigned long long*)(smem + 62496);

    const int b = blockIdx.x, t = threadIdx.x;
    const int l = t & 63, l15 = l & 15, lg = l >> 4;
    const int w = __builtin_amdgcn_readfirstlane(t >> 6);
    // GEMM role: each (pass-ct, row-tile) owned by exactly one wave-pair -> weights read 2x/block (L1-absorbed)
    const int g_rt0 = 2 * (w & 1);       // row-tiles {g_rt0, g_rt0+1}
    const int g_pc0 = 3 * (w >> 1);      // pass-col-tiles {g_pc0..g_pc0+2} of 12
    // attention role: 4 waves per head, each owns a 16-row S strip
    const int hg = w >> 2;               // local head 0/1
    const int rs = w & 3;                // S row strip

    // stage rpb table + masks
    for (int i = t; i < 1800; i += 512) rpb_l[i] = rpb_table[i];
    if (t < 64) mask_l[t] = masks[(size_t)b * 64 + t];

    const float* xp = x + (size_t)b * (NT * DIMC);
    float* op = aout + (size_t)b * (NT * DIMC);

    for (int pass = 0; pass < 4; ++pass) {
        // ---- phase 1: qkv GEMM for heads (2*pass, 2*pass+1); x A-frags from global fp32 ----
        f32x4 acc[3][2];
        #pragma unroll
        for (int c = 0; c < 3; ++c) {
            const int pc = g_pc0 + c, mat = pc >> 2, within = pc & 3;
            const float bv = qkv_b[mat * 256 + (4 * pass + within) * 16 + l15];
            acc[c][0] = (f32x4){bv, bv, bv, bv};
            acc[c][1] = (f32x4){bv, bv, bv, bv};
        }
        for (int ks = 0; ks < 8; ++ks) {
            const float* a0p = xp + (g_rt0 * 16 + l15) * 256 + ks * 32 + lg * 8;
            const float* a1p = a0p + 16 * 256;
            float av0[8], av1[8];
            *reinterpret_cast<float4*>(&av0[0]) = *reinterpret_cast<const float4*>(a0p);
            *reinterpret_cast<float4*>(&av0[4]) = *reinterpret_cast<const float4*>(a0p + 4);
            *reinterpret_cast<float4*>(&av1[0]) = *reinterpret_cast<const float4*>(a1p);
            *reinterpret_cast<float4*>(&av1[4]) = *reinterpret_cast<const float4*>(a1p + 4);
            bf16x8 ah0, al0, ah1, al1;
            cvt8(av0, ah0, al0);
            cvt8(av1, ah1, al1);
            #pragma unroll
            for (int c = 0; c < 3; ++c) {
                const int pc = g_pc0 + c, mat = pc >> 2, within = pc & 3;
                const int ct = mat * 16 + 4 * pass + within;
                const bf16x8 bh = *reinterpret_cast<const bf16x8*>(wqhi + ct * 4096 + ks * 512 + l * 8);
                const bf16x8 bl = *reinterpret_cast<const bf16x8*>(wqlo + ct * 4096 + ks * 512 + l * 8);
                acc[c][0] = MFMA16(ah0, bh, acc[c][0], 0, 0, 0);
                acc[c][0] = MFMA16(ah0, bl, acc[c][0], 0, 0, 0);
                acc[c][0] = MFMA16(al0, bh, acc[c][0], 0, 0, 0);
                acc[c][1] = MFMA16(ah1, bh, acc[c][1], 0, 0, 0);
                acc[c][1] = MFMA16(ah1, bl, acc[c][1], 0, 0, 0);
                acc[c][1] = MFMA16(al1, bh, acc[c][1], 0, 0, 0);
            }
        }
        // write q/k (row-major, +SCALE on q) and v transposed, all bf16 hi/lo
        #pragma unroll
        for (int c = 0; c < 3; ++c) {
            const int pc = g_pc0 + c, mat = pc >> 2, within = pc & 3;
            const int hh = within >> 1, dh = within & 1;
            #pragma unroll
            for (int rtl = 0; rtl < 2; ++rtl) {
                const int tok0 = (g_rt0 + rtl) * 16 + 4 * lg;
                #pragma unroll
                for (int r = 0; r < 4; ++r) {
                    float val = acc[c][rtl][r];
                    const int tok = tok0 + r;
                    if (mat == 0) {
                        val *= SCALE_;
                        const unsigned short hv = f2bf(val);
                        qhi[tok * 72 + hh * 32 + dh * 16 + l15] = hv;
                        qlo[tok * 72 + hh * 32 + dh * 16 + l15] = f2bf(val - bf2f(hv));
                    } else if (mat == 1) {
                        const unsigned short hv = f2bf(val);
                        khi[tok * 72 + hh * 32 + dh * 16 + l15] = hv;
                        klo[tok * 72 + hh * 32 + dh * 16 + l15] = f2bf(val - bf2f(hv));
                    } else {
                        const int d = dh * 16 + l15;
                        const unsigned short hv = f2bf(val);
                        vThi[hh * 2304 + d * 72 + tok] = hv;
                        vTlo[hh * 2304 + d * 72 + tok] = f2bf(val - bf2f(hv));
                    }
                }
            }
        }
        __syncthreads();   // (1) q/k/vT ready

        // ---- phase 2: QK^T (head h = 2*pass + hg, rows rs*16..+16) ----
        const int h = 2 * pass + hg;
        const bf16x8 aqh = *reinterpret_cast<const bf16x8*>(&qhi[(rs * 16 + l15) * 72 + hg * 32 + lg * 8]);
        const bf16x8 aql = *reinterpret_cast<const bf16x8*>(&qlo[(rs * 16 + l15) * 72 + hg * 32 + lg * 8]);
        f32x4 s[4];
        #pragma unroll
        for (int cs = 0; cs < 4; ++cs) {
            const bf16x8 bkh = *reinterpret_cast<const bf16x8*>(&khi[(cs * 16 + l15) * 72 + hg * 32 + lg * 8]);
            const bf16x8 bkl = *reinterpret_cast<const bf16x8*>(&klo[(cs * 16 + l15) * 72 + hg * 32 + lg * 8]);
            f32x4 z = (f32x4){0.f, 0.f, 0.f, 0.f};
            z = MFMA16(aqh, bkh, z, 0, 0, 0);
            z = MFMA16(aqh, bkl, z, 0, 0, 0);
            z = MFMA16(aql, bkh, z, 0, 0, 0);
            s[cs] = z;
        }
        // modulation + rpb + softmax (exact fp32 semantics)
        const int srow0 = rs * 16 + 4 * lg;
        unsigned long long mw[4];
        #pragma unroll
        for (int r = 0; r < 4; ++r) mw[r] = mask_l[srow0 + r];
        float pbuf[4][4], mx[4], sm[4], inv[4];
        #pragma unroll
        for (int r = 0; r < 4; ++r) mx[r] = -1e30f;
        #pragma unroll
        for (int cs = 0; cs < 4; ++cs) {
            const int scol = cs * 16 + l15;
            #pragma unroll
            for (int r = 0; r < 4; ++r) {
                const int srow = srow0 + r;
                float sv = s[cs][r];
                sv *= ((mw[r] >> scol) & 1ull) ? 1.0f : 1.2f;
                const int ridx = ((srow >> 3) - (scol >> 3) + 7) * 15 + ((srow & 7) - (scol & 7) + 7);
                sv += rpb_l[ridx * NHEADS + h];
                pbuf[r][cs] = sv;
                mx[r] = fmaxf(mx[r], sv);
            }
        }
        #pragma unroll
        for (int r = 0; r < 4; ++r) {
            mx[r] = fmaxf(mx[r], __shfl_xor(mx[r], 1));
            mx[r] = fmaxf(mx[r], __shfl_xor(mx[r], 2));
            mx[r] = fmaxf(mx[r], __shfl_xor(mx[r], 4));
            mx[r] = fmaxf(mx[r], __shfl_xor(mx[r], 8));
            sm[r] = 0.f;
        }
        #pragma unroll
        for (int cs = 0; cs < 4; ++cs)
            #pragma unroll
            for (int r = 0; r < 4; ++r) {
                pbuf[r][cs] = __expf(pbuf[r][cs] - mx[r]);
                sm[r] += pbuf[r][cs];
            }
        #pragma unroll
        for (int r = 0; r < 4; ++r) {
            sm[r] += __shfl_xor(sm[r], 1);
            sm[r] += __shfl_xor(sm[r], 2);
            sm[r] += __shfl_xor(sm[r], 4);
            sm[r] += __shfl_xor(sm[r], 8);
            inv[r] = 1.f / sm[r];
        }
        __syncthreads();   // (2) all q/k reads done; P may now overwrite that space

        #pragma unroll
        for (int cs = 0; cs < 4; ++cs) {
            const int scol = cs * 16 + l15;
            #pragma unroll
            for (int r = 0; r < 4; ++r) {
                const float pp = pbuf[r][cs] * inv[r];
                const unsigned short ph = f2bf(pp);
                phi[hg * 4608 + (srow0 + r) * 72 + scol] = ph;
                plo[hg * 4608 + (srow0 + r) * 72 + scol] = f2bf(pp - bf2f(ph));
            }
        }
        __syncthreads();   // (3) P ready

        // ---- phase 3: PV (out rows rs*16..+16, head h) ----
        #pragma unroll
        for (int dt = 0; dt < 2; ++dt) {
            f32x4 o_ = (f32x4){0.f, 0.f, 0.f, 0.f};
            #pragma unroll
            for (int k2 = 0; k2 < 2; ++k2) {
                const bf16x8 pah = *reinterpret_cast<const bf16x8*>(&phi[hg * 4608 + (rs * 16 + l15) * 72 + k2 * 32 + lg * 8]);
                const bf16x8 pal = *reinterpret_cast<const bf16x8*>(&plo[hg * 4608 + (rs * 16 + l15) * 72 + k2 * 32 + lg * 8]);
                const bf16x8 vbh = *reinterpret_cast<const bf16x8*>(&vThi[hg * 2304 + (dt * 16 + l15) * 72 + k2 * 32 + lg * 8]);
                const bf16x8 vbl = *reinterpret_cast<const bf16x8*>(&vTlo[hg * 2304 + (dt * 16 + l15) * 72 + k2 * 32 + lg * 8]);
                o_ = MFMA16(pah, vbh, o_, 0, 0, 0);
                o_ = MFMA16(pah, vbl, o_, 0, 0, 0);
                o_ = MFMA16(pal, vbh, o_, 0, 0, 0);
            }
            #pragma unroll
            for (int r = 0; r < 4; ++r)
                op[(srow0 + r) * 256 + h * 32 + dt * 16 + l15] = o_[r];
        }
        __syncthreads();   // (4) p/vT reads done before next pass overwrites
    }
}

// ---------------- kernel 3: out projection via split-bf16 MFMA, in-place (unchanged, passed) ----------------
__global__ __launch_bounds__(512) void k_proj(
    const float* __restrict__ proj_b,
    const unsigned short* __restrict__ wphi,
    const unsigned short* __restrict__ wplo,
    float* __restrict__ inout)
{
    __shared__ alignas(16) unsigned short ahi[64][264];
    __shared__ alignas(16) unsigned short alo[64][264];
    const int b = blockIdx.x, t = threadIdx.x;
    const int l = t & 63;
    const int wave = __builtin_amdgcn_readfirstlane(t >> 6);

    float* base = inout + (size_t)b * (NT * DIMC);
    #pragma unroll
    for (int i = 0; i < 8; ++i) {
        int idx = t + i * 512;
        float4 v = reinterpret_cast<const float4*>(base)[idx];
        int n = idx >> 6, kq = (idx & 63) << 2;
        ushort4 h, lo;
        h.x = f2bf(v.x); h.y = f2bf(v.y); h.z = f2bf(v.z); h.w = f2bf(v.w);
        lo.x = f2bf(v.x - bf2f(h.x)); lo.y = f2bf(v.y - bf2f(h.y));
        lo.z = f2bf(v.z - bf2f(h.z)); lo.w = f2bf(v.w - bf2f(h.w));
        *reinterpret_cast<ushort4*>(&ahi[n][kq]) = h;
        *reinterpret_cast<ushort4*>(&alo[n][kq]) = lo;
    }
    __syncthreads();

    const int kgrp = 8 * (l >> 4);
    f32x4 acc[2][4];                      // [ct-local][rt]
    #pragma unroll
    for (int c = 0; c < 2; ++c) {
        const int col = (2 * wave + c) * 16 + (l & 15);
        const float bv = proj_b[col];
        #pragma unroll
        for (int r = 0; r < 4; ++r) acc[c][r] = (f32x4){bv, bv, bv, bv};
    }
    for (int ks = 0; ks < 8; ++ks) {
        bf16x8 ah0 = *reinterpret_cast<const bf16x8*>(&ahi[ 0 + (l & 15)][ks * 32 + kgrp]);
        bf16x8 al0 = *reinterpret_cast<const bf16x8*>(&alo[ 0 + (l & 15)][ks * 32 + kgrp]);
        bf16x8 ah1 = *reinterpret_cast<const bf16x8*>(&ahi[16 + (l & 15)][ks * 32 + kgrp]);
        bf16x8 al1 = *reinterpret_cast<const bf16x8*>(&alo[16 + (l & 15)][ks * 32 + kgrp]);
        bf16x8 ah2 = *reinterpret_cast<const bf16x8*>(&ahi[32 + (l & 15)][ks * 32 + kgrp]);
        bf16x8 al2 = *reinterpret_cast<const bf16x8*>(&alo[32 + (l & 15)][ks * 32 + kgrp]);
        bf16x8 ah3 = *reinterpret_cast<const bf16x8*>(&ahi[48 + (l & 15)][ks * 32 + kgrp]);
        bf16x8 al3 = *reinterpret_cast<const bf16x8*>(&alo[48 + (l & 15)][ks * 32 + kgrp]);
        #pragma unroll
        for (int c = 0; c < 2; ++c) {
            const int ct = 2 * wave + c;
            const int off = ct * 4096 + ks * 512 + l * 8;
            const bf16x8 bh = *reinterpret_cast<const bf16x8*>(wphi + off);
            const bf16x8 bl = *reinterpret_cast<const bf16x8*>(wplo + off);
            acc[c][0] = MFMA16(ah0, bh, acc[c][0], 0, 0, 0);
            acc[c][0] = MFMA16(ah0, bl, acc[c][0], 0, 0, 0);
            acc[c][0] = MFMA16(al0, bh, acc[c][0], 0, 0, 0);
            acc[c][1] = MFMA16(ah1, bh, acc[c][1], 0, 0, 0);
            acc[c][1] = MFMA16(ah1, bl, acc[c][1], 0, 0, 0);
            acc[c][1] = MFMA16(al1, bh, acc[c][1], 0, 0, 0);
            acc[c][2] = MFMA16(ah2, bh, acc[c][2], 0, 0, 0);
            acc[c][2] = MFMA16(ah2, bl, acc[c][2], 0, 0, 0);
            acc[c][2] = MFMA16(al2, bh, acc[c][2], 0, 0, 0);
            acc[c][3] = MFMA16(ah3, bh, acc[c][3], 0, 0, 0);
            acc[c][3] = MFMA16(ah3, bl, acc[c][3], 0, 0, 0);
            acc[c][3] = MFMA16(al3, bh, acc[c][3], 0, 0, 0);
        }
    }
    {
        const int rowo = 4 * (l >> 4);
        #pragma unroll
        for (int c = 0; c < 2; ++c) {
            const int col = (2 * wave + c) * 16 + (l & 15);
            #pragma unroll
            for (int rt = 0; rt < 4; ++rt) {
                #pragma unroll
                for (int r = 0; r < 4; ++r)
                    base[(rt * 16 + rowo + r) * 256 + col] = acc[c][rt][r];
            }
        }
    }
}

extern "C" void kernel_launch(void* const* d_in, const int* in_sizes, int n_in,
                              void* d_out, int out_size, void* d_ws, size_t ws_size,
                              hipStream_t stream)
{
    const float* x      = (const float*)d_in[0];
    const float* var    = (const float*)d_in[1];
    const float* qkv_w  = (const float*)d_in[2];
    const float* qkv_b  = (const float*)d_in[3];
    const float* proj_w = (const float*)d_in[4];
    const float* proj_b = (const float*)d_in[5];
    const float* rpb    = (const float*)d_in[6];
    float* out = (float*)d_out;

    unsigned short* wqhi = (unsigned short*)d_ws;          // 196608
    unsigned short* wqlo = wqhi + 196608;                  // 196608
    unsigned short* wphi = wqlo + 196608;                  // 65536
    unsigned short* wplo = wphi + 65536;                   // 65536
    unsigned long long* masks = (unsigned long long*)((char*)d_ws + 1048576);

    k_prep      <<<1024, 256, 0, stream>>>(qkv_w, proj_w, wqhi, wqlo, wphi, wplo);
    k_modulation<<<NWIN, 256, 0, stream>>>(var, masks);
    k_attn      <<<NWIN, 512, 0, stream>>>(x, qkv_b, rpb, wqhi, wqlo, masks, out);
    k_proj      <<<NWIN, 512, 0, stream>>>(proj_b, wphi, wplo, out);
}